// Round 8
// baseline (420.173 us; speedup 1.0000x reference)
//
#include <hip/hip_runtime.h>

// GIN: 3 layers of {agg = scatter_sum(h[src] -> dst); h = relu(((1+eps)h + agg) @ W + b)}
// then per-graph segment-sum readout (graph_ids sorted) -> 2-layer MLP.
//
// R8: (a) XCD-replicated histogram: degrep[8][N], chunk c uses replica c&7
//     (linear dispatch -> XCD c%8) so deg-atomic lines stop bouncing across
//     XCDs (R7: hist 52us, 42MB fabric writes for 5MB of data). combine pass
//     makes deg + per-replica offsets; fill adds repoff[r_i][d] to local rank.
//     (b) agg gather unroll 4 -> 8.
// R7: dense rank, f16 H. R6: XCD-local fill. R5: agg/MFMA-gemm split.
// absmax note: output compared in bf16 space (ulp@7e4=512); 1280 = 2.5 ulp.

#define SPLIT 16
#define CHUNK 1024   // edges per chunk; replica/range key = chunk & 7

typedef unsigned short ushort_t;
typedef __bf16 v8bf __attribute__((ext_vector_type(8)));
typedef float v4f __attribute__((ext_vector_type(4)));

__device__ __forceinline__ float h2f_lo(unsigned int v) {
    return (float)__builtin_bit_cast(_Float16, (unsigned short)(v & 0xffffu));
}
__device__ __forceinline__ float h2f_hi(unsigned int v) {
    return (float)__builtin_bit_cast(_Float16, (unsigned short)(v >> 16));
}
__device__ __forceinline__ unsigned int f2h(float f) {
    return (unsigned int)__builtin_bit_cast(unsigned short, (_Float16)f);
}

__global__ void cast_kernel(const float* __restrict__ x, ushort_t* __restrict__ xh, int n4) {
    int i = blockIdx.x * blockDim.x + threadIdx.x;
    if (i < n4) {
        float4 v = ((const float4*)x)[i];
        uint2 p;
        p.x = f2h(v.x) | (f2h(v.y) << 16);
        p.y = f2h(v.z) | (f2h(v.w) << 16);
        ((uint2*)xh)[i] = p;
    }
}

// W[l][k][n] f32 -> Wt_hi/Wt_lo[l][n][k] bf16 (transposed, hi+lo split)
__global__ void prep_w_kernel(const float* __restrict__ W,
                              ushort_t* __restrict__ whi, ushort_t* __restrict__ wlo,
                              int total) {
    int i = blockIdx.x * blockDim.x + threadIdx.x;
    if (i >= total) return;
    int l = i >> 12, r = i & 4095;
    int n = r >> 6, k = r & 63;
    float w = W[l * 4096 + k * 64 + n];
    __bf16 h = (__bf16)w;
    float rem = w - (float)h;
    __bf16 lo = (__bf16)rem;
    whi[i] = __builtin_bit_cast(ushort_t, h);
    wlo[i] = __builtin_bit_cast(ushort_t, lo);
}

// Replicated histogram: chunk c -> replica r = c&7. Linear dispatch puts
// chunk c on XCD c%8, so replica r's lines live in one XCD's L2.
__global__ __launch_bounds__(256) void hist_kernel(const int* __restrict__ dst,
                                                   int* __restrict__ degrep,
                                                   int* __restrict__ rank,
                                                   int E, int N) {
    int chunk = blockIdx.x;
    int r = chunk & 7;
    int base = chunk * CHUNK;
    int end = min(base + CHUNK, E);
    int* degr = degrep + (size_t)r * N;
    for (int i = base + threadIdx.x; i < end; i += 256)
        rank[i] = atomicAdd(&degr[dst[i]], 1);
}

// deg[d] = sum_r degrep[r][d]; repoff[r][d] = exclusive prefix over r.
__global__ void combine_kernel(const int* __restrict__ degrep,
                               int* __restrict__ repoff,
                               int* __restrict__ deg, int N) {
    int d = blockIdx.x * blockDim.x + threadIdx.x;
    if (d >= N) return;
    int s = 0;
    #pragma unroll
    for (int r = 0; r < 8; ++r) {
        repoff[(size_t)r * N + d] = s;
        s += degrep[(size_t)r * N + d];
    }
    deg[d] = s;
}

// --- 3-phase parallel scan over deg[N] -> offsets[N+1] ---
__global__ __launch_bounds__(256) void scan_part_kernel(const int* __restrict__ deg,
                                                        int* __restrict__ bsum, int N) {
    __shared__ int sh[256];
    int t = threadIdx.x;
    int i = (blockIdx.x * 256 + t) * 2;
    int s = 0;
    if (i < N) s += deg[i];
    if (i + 1 < N) s += deg[i + 1];
    sh[t] = s;
    __syncthreads();
    for (int off = 128; off > 0; off >>= 1) {
        if (t < off) sh[t] += sh[t + off];
        __syncthreads();
    }
    if (t == 0) bsum[blockIdx.x] = sh[0];
}

__global__ __launch_bounds__(256) void scan_mid_kernel(const int* __restrict__ bsum,
                                                       int* __restrict__ boff, int nb) {
    __shared__ int sh[256];
    int t = threadIdx.x;
    int v = (t < nb) ? bsum[t] : 0;
    sh[t] = v;
    __syncthreads();
    for (int off = 1; off < 256; off <<= 1) {
        int u = (t >= off) ? sh[t - off] : 0;
        __syncthreads();
        sh[t] += u;
        __syncthreads();
    }
    if (t < nb) boff[t] = sh[t] - v;
}

__global__ __launch_bounds__(256) void scan_final_kernel(const int* __restrict__ deg,
                                                         const int* __restrict__ boff,
                                                         int* __restrict__ offsets,
                                                         int N, int E) {
    __shared__ int sh[256];
    int t = threadIdx.x;
    int i = (blockIdx.x * 256 + t) * 2;
    int d0 = (i < N) ? deg[i] : 0;
    int d1 = (i + 1 < N) ? deg[i + 1] : 0;
    int s = d0 + d1;
    sh[t] = s;
    __syncthreads();
    for (int off = 1; off < 256; off <<= 1) {
        int u = (t >= off) ? sh[t - off] : 0;
        __syncthreads();
        sh[t] += u;
        __syncthreads();
    }
    int pre = boff[blockIdx.x] + sh[t] - s;
    if (i < N) offsets[i] = pre;
    if (i + 1 < N) offsets[i + 1] = pre + d0;
    if (blockIdx.x == 0 && t == 0) offsets[N] = E;
}

// 8-range fill, atomic-free: csr[offsets[d] + repoff[r_i][d] + rank[i]] = src[i]
// where r_i = (i/CHUNK)&7 (the replica edge i used in hist). Each csr segment
// belongs to one dst-range -> written by ~one XCD.
__global__ __launch_bounds__(256) void fill_kernel(const int* __restrict__ src,
                                                   const int* __restrict__ dst,
                                                   const int* __restrict__ offsets,
                                                   const int* __restrict__ repoff,
                                                   const int* __restrict__ rank,
                                                   int* __restrict__ csr,
                                                   int E, int N, int rsize) {
    int chunk = blockIdx.x >> 3;
    int range = blockIdx.x & 7;
    int rlo = range * rsize, rhi = rlo + rsize;
    int base = chunk * CHUNK;
    int end = min(base + CHUNK, E);
    int r = chunk & 7;   // replica used by this chunk in hist
    const int* rep = repoff + (size_t)r * N;
    for (int i = base + threadIdx.x; i < end; i += 256) {
        int d = dst[i];
        if (d >= rlo && d < rhi)
            csr[offsets[d] + rep[d] + rank[i]] = src[i];
    }
}

// One wave per node. Preload <=64 csr indices (one coalesced load), broadcast
// with shfl; unroll-8 gather loop -> ~8 independent 128B row loads in flight.
// lane = g*16+sl: group g handles edges j = g, g+4, ...; 16 lanes x uint2 = row.
__global__ __launch_bounds__(256) void agg_kernel(
        const ushort_t* __restrict__ hin, float* __restrict__ agg,
        const int* __restrict__ offsets, const int* __restrict__ csr,
        const float* __restrict__ eps_arr, int layer, int N) {
    int lane = threadIdx.x & 63;
    int wave = threadIdx.x >> 6;
    int n = blockIdx.x * 4 + wave;
    if (n >= N) return;
    float eps1 = 1.0f + eps_arr[layer];

    int g  = lane >> 4;    // edge group 0..3
    int sl = lane & 15;    // uint2 slot within row (dims 4sl..4sl+3)

    int e0 = offsets[n], e1 = offsets[n + 1];
    int deg = e1 - e0;
    int idx = (lane < deg) ? csr[e0 + lane] : 0;
    int dcap = min(deg, 64);

    float ax = 0.f, ay = 0.f, az = 0.f, aw = 0.f;
    #pragma unroll 8
    for (int j = g; j < dcap; j += 4) {
        int s = __shfl(idx, j, 64);
        uint2 v = ((const uint2*)(hin + (size_t)s * 64))[sl];
        ax += h2f_lo(v.x); ay += h2f_hi(v.x); az += h2f_lo(v.y); aw += h2f_hi(v.y);
    }
    // rare tail: deg > 64
    for (int e = e0 + 64 + g; e < e1; e += 4) {
        int s = csr[e];
        uint2 v = ((const uint2*)(hin + (size_t)s * 64))[sl];
        ax += h2f_lo(v.x); ay += h2f_hi(v.x); az += h2f_lo(v.y); aw += h2f_hi(v.y);
    }

    ax += __shfl_xor(ax, 16, 64); ax += __shfl_xor(ax, 32, 64);
    ay += __shfl_xor(ay, 16, 64); ay += __shfl_xor(ay, 32, 64);
    az += __shfl_xor(az, 16, 64); az += __shfl_xor(az, 32, 64);
    aw += __shfl_xor(aw, 16, 64); aw += __shfl_xor(aw, 32, 64);

    uint2 self = ((const uint2*)(hin + (size_t)n * 64))[sl];
    ax = fmaf(eps1, h2f_lo(self.x), ax);
    ay = fmaf(eps1, h2f_hi(self.x), ay);
    az = fmaf(eps1, h2f_lo(self.y), az);
    aw = fmaf(eps1, h2f_hi(self.y), aw);

    if (g == 0) {
        float4 v; v.x = ax; v.y = ay; v.z = az; v.w = aw;
        ((float4*)(agg + (size_t)n * 64))[sl] = v;
    }
}

// h_out[node][d] = relu(b[d] + sum_k agg[node][k] * W[k][d]) via MFMA.
// A = Wt (hi/lo bf16), B = agg rows (hi/lo bf16 in-register), 3-MFMA split product.
// One wave = 16 nodes. Zero LDS. H written f16.
__global__ __launch_bounds__(256) void gemm_kernel(
        const float* __restrict__ agg, ushort_t* __restrict__ hout,
        const ushort_t* __restrict__ wt_hi, const ushort_t* __restrict__ wt_lo,
        const float* __restrict__ gin_b, int layer, int N) {
    int wave = threadIdx.x >> 6;
    int lane = threadIdx.x & 63;
    int tile = blockIdx.x * 4 + wave;
    if (tile * 16 >= N) return;
    int c = lane & 15;     // node within tile / n-index
    int q = lane >> 4;     // quad
    int node = tile * 16 + c;
    int lnode = min(node, N - 1);   // clamp loads; stores guarded below

    const ushort_t* Whi = wt_hi + layer * 4096;
    const ushort_t* Wlo = wt_lo + layer * 4096;
    const float*    bl  = gin_b + layer * 64;

    // B-frags: agg[node][k], k = kt*32 + q*8 + j
    v8bf bhi[2], blo2[2];
    #pragma unroll
    for (int kt = 0; kt < 2; ++kt) {
        const float* p = agg + (size_t)lnode * 64 + kt * 32 + q * 8;
        float4 f0 = ((const float4*)p)[0];
        float4 f1 = ((const float4*)p)[1];
        float xs[8] = {f0.x, f0.y, f0.z, f0.w, f1.x, f1.y, f1.z, f1.w};
        #pragma unroll
        for (int j = 0; j < 8; ++j) {
            __bf16 h = (__bf16)xs[j];
            bhi[kt][j] = h;
            blo2[kt][j] = (__bf16)(xs[j] - (float)h);
        }
    }

    #pragma unroll
    for (int mt = 0; mt < 4; ++mt) {
        v4f acc = {0.f, 0.f, 0.f, 0.f};
        #pragma unroll
        for (int kt = 0; kt < 2; ++kt) {
            int dim = mt * 16 + c;
            size_t off = (size_t)dim * 64 + kt * 32 + q * 8;
            v8bf ah = __builtin_bit_cast(v8bf, *(const uint4*)(Whi + off));
            v8bf al = __builtin_bit_cast(v8bf, *(const uint4*)(Wlo + off));
            acc = __builtin_amdgcn_mfma_f32_16x16x32_bf16(ah, bhi[kt],  acc, 0, 0, 0);
            acc = __builtin_amdgcn_mfma_f32_16x16x32_bf16(ah, blo2[kt], acc, 0, 0, 0);
            acc = __builtin_amdgcn_mfma_f32_16x16x32_bf16(al, bhi[kt],  acc, 0, 0, 0);
        }
        float4 bv = ((const float4*)(bl + mt * 16))[q];   // dims mt*16+q*4 .. +3
        float o0 = fmaxf(acc[0] + bv.x, 0.f);
        float o1 = fmaxf(acc[1] + bv.y, 0.f);
        float o2 = fmaxf(acc[2] + bv.z, 0.f);
        float o3 = fmaxf(acc[3] + bv.w, 0.f);
        uint2 pk;
        pk.x = f2h(o0) | (f2h(o1) << 16);
        pk.y = f2h(o2) | (f2h(o3) << 16);
        if (node < N)
            *(uint2*)(hout + (size_t)node * 64 + mt * 16 + q * 4) = pk;
    }
}

// 256 graphs x SPLIT splits; 192 threads (t = l*64+d); f16 H, f32 accumulate.
__global__ __launch_bounds__(192) void readout_kernel(
        const ushort_t* __restrict__ H, const int* __restrict__ gids,
        float* __restrict__ g, int N) {
    int graph = blockIdx.x / SPLIT;
    int sp    = blockIdx.x % SPLIT;
    int lo = 0, hi = N;
    while (lo < hi) { int mid = (lo + hi) >> 1; if (gids[mid] < graph) lo = mid + 1; else hi = mid; }
    int start = lo;
    int lo2 = start, hi2 = N;
    while (lo2 < hi2) { int mid = (lo2 + hi2) >> 1; if (gids[mid] < graph + 1) lo2 = mid + 1; else hi2 = mid; }
    int end = lo2;
    int cnt = end - start;
    if (cnt <= 0) return;
    int per = (cnt + SPLIT - 1) / SPLIT;
    int cs = start + sp * per;
    int ce = min(cs + per, end);
    if (cs >= ce) return;

    int t = threadIdx.x;            // 0..191
    int l = t >> 6, d = t & 63;
    const ushort_t* Hl = H + (size_t)l * N * 64;
    float acc = 0.0f;
    for (int n = cs; n < ce; ++n)
        acc += (float)__builtin_bit_cast(_Float16, Hl[(size_t)n * 64 + d]);
    atomicAdd(&g[graph * 192 + t], acc);
}

__global__ __launch_bounds__(192) void mlp_kernel(
        const float* __restrict__ g,
        const float* __restrict__ W1, const float* __restrict__ b1,
        const float* __restrict__ W2, const float* __restrict__ b2,
        float* __restrict__ out) {
    __shared__ float gr[192];
    __shared__ float hid[128];
    int graph = blockIdx.x;
    int t = threadIdx.x;
    gr[t] = g[graph * 192 + t];
    __syncthreads();
    if (t < 128) {
        float a = b1[t];
        for (int k = 0; k < 192; ++k) a = fmaf(gr[k], W1[k * 128 + t], a);
        hid[t] = fmaxf(a, 0.0f);
    }
    __syncthreads();
    if (t < 32) {
        float a = b2[t];
        for (int k = 0; k < 128; ++k) a = fmaf(hid[k], W2[k * 32 + t], a);
        out[graph * 32 + t] = a;
    }
}

extern "C" void kernel_launch(void* const* d_in, const int* in_sizes, int n_in,
                              void* d_out, int out_size, void* d_ws, size_t ws_size,
                              hipStream_t stream) {
    const float* x     = (const float*)d_in[0];
    const float* gin_W = (const float*)d_in[1];
    const float* gin_b = (const float*)d_in[2];
    const float* eps   = (const float*)d_in[3];
    const float* r_W1  = (const float*)d_in[4];
    const float* r_b1  = (const float*)d_in[5];
    const float* r_W2  = (const float*)d_in[6];
    const float* r_b2  = (const float*)d_in[7];
    const int*   src   = (const int*)d_in[8];
    const int*   dst   = (const int*)d_in[9];
    const int*   gids  = (const int*)d_in[10];

    int N = in_sizes[0] / 64;       // 100000
    int E = in_sizes[8];            // 1200000
    int B = out_size / 32;          // 256

    // workspace layout (4B words):
    //   degrep[8N] | g[B*192]                  <- zeroed
    //   repoff[8N] | deg[N] | offsets[N+1] | csr[E] | rank[E] | bsum | boff | pad
    //   xh[N*64 f16] | H[3*N*64 f16] | whi[3*4096] | wlo[3*4096] | pad | agg[N*64 f32]
    int nb_scan = (N + 511) / 512;
    int* ws       = (int*)d_ws;
    int* degrep   = ws;
    float* g      = (float*)(ws + 8 * (size_t)N);
    int* repoff   = ws + 8 * (size_t)N + B * 192;
    int* deg      = repoff + 8 * (size_t)N;
    int* offsets  = deg + N;
    int* csr      = offsets + (N + 1);
    int* rank     = csr + E;
    int* bsum     = rank + E;
    int* boff     = bsum + nb_scan;
    size_t w      = (size_t)(boff + nb_scan - ws);
    w = (w + 15) & ~(size_t)15;     // 64B align
    ushort_t* xh  = (ushort_t*)(ws + w);
    ushort_t* H   = xh + (size_t)N * 64;
    ushort_t* whi = H + 3 * (size_t)N * 64;
    ushort_t* wlo = whi + 3 * 4096;
    size_t w2     = ((size_t)((int*)(wlo + 3 * 4096) - ws) + 15) & ~(size_t)15;
    float* agg    = (float*)(ws + w2);

    size_t zero_bytes = (8 * (size_t)N + (size_t)B * 192) * sizeof(int);
    hipMemsetAsync(d_ws, 0, zero_bytes, stream);

    int rsize = (N + 7) / 8;                 // dst-range size per fill pass
    int nchunks = (E + CHUNK - 1) / CHUNK;
    cast_kernel<<<(N * 64 / 4 + 255) / 256, 256, 0, stream>>>(x, xh, N * 64 / 4);
    prep_w_kernel<<<(3 * 4096 + 255) / 256, 256, 0, stream>>>(gin_W, whi, wlo, 3 * 4096);
    hist_kernel<<<nchunks, 256, 0, stream>>>(dst, degrep, rank, E, N);
    combine_kernel<<<(N + 255) / 256, 256, 0, stream>>>(degrep, repoff, deg, N);
    scan_part_kernel<<<nb_scan, 256, 0, stream>>>(deg, bsum, N);
    scan_mid_kernel<<<1, 256, 0, stream>>>(bsum, boff, nb_scan);
    scan_final_kernel<<<nb_scan, 256, 0, stream>>>(deg, boff, offsets, N, E);
    fill_kernel<<<nchunks * 8, 256, 0, stream>>>(src, dst, offsets, repoff, rank, csr, E, N, rsize);

    int nbk = (N + 3) / 4;                       // agg: wave per node, 4/block
    int gbk = ((N + 15) / 16 + 3) / 4;           // gemm: wave per 16 nodes, 4/block
    ushort_t* H0 = H;
    ushort_t* H1 = H + (size_t)N * 64;
    ushort_t* H2 = H + 2 * (size_t)N * 64;

    agg_kernel<<<nbk, 256, 0, stream>>>(xh, agg, offsets, csr, eps, 0, N);
    gemm_kernel<<<gbk, 256, 0, stream>>>(agg, H0, whi, wlo, gin_b, 0, N);
    agg_kernel<<<nbk, 256, 0, stream>>>(H0, agg, offsets, csr, eps, 1, N);
    gemm_kernel<<<gbk, 256, 0, stream>>>(agg, H1, whi, wlo, gin_b, 1, N);
    agg_kernel<<<nbk, 256, 0, stream>>>(H1, agg, offsets, csr, eps, 2, N);
    gemm_kernel<<<gbk, 256, 0, stream>>>(agg, H2, whi, wlo, gin_b, 2, N);

    readout_kernel<<<B * SPLIT, 192, 0, stream>>>(H, gids, g, N);
    mlp_kernel<<<B, 192, 0, stream>>>(g, r_W1, r_b1, r_W2, r_b2, (float*)d_out);
}

// Round 9
// 373.847 us; speedup vs baseline: 1.1239x; 1.1239x over previous
//
#include <hip/hip_runtime.h>

// GIN: 3 layers of {agg = scatter_sum(h[src] -> dst); h = relu(((1+eps)h + agg) @ W + b)}
// then per-graph segment-sum readout (graph_ids sorted) -> 2-layer MLP.
//
// R9: atomic-free bucketed CSR build. R8 falsified XCD-replication: global
//     atomics execute at the IC coherence point (~32B write/op regardless of
//     locality; 1.2M ops = 42MB = the whole hist cost). New build:
//     A) per-block LDS hist -> dense cnt2d    (no global atomics)
//     B1) per-bucket column scan -> block slots  B2) bucket base scan
//     C) scatter packed (src<<9|dlocal) into bucket regions, LDS rank only
//     D) per-bucket LDS hist+scan -> offsets + csr, LDS atomics only
// R7: dense rank, f16 H. R6: XCD-local fill. R5: agg/MFMA-gemm split.
// absmax note: pinned at 1280 across bf16/f16/order changes -> input-quant
// dominated, order-insensitive. bf16-ulp@7e4=512; threshold 1495.

#define SPLIT 16
#define NBLK 512     // edge chunks for bucket build
#define BS 512       // nodes per bucket (pow2; d_local = d & 511, bucket = d >> 9)

typedef unsigned short ushort_t;
typedef __bf16 v8bf __attribute__((ext_vector_type(8)));
typedef float v4f __attribute__((ext_vector_type(4)));

__device__ __forceinline__ float h2f_lo(unsigned int v) {
    return (float)__builtin_bit_cast(_Float16, (unsigned short)(v & 0xffffu));
}
__device__ __forceinline__ float h2f_hi(unsigned int v) {
    return (float)__builtin_bit_cast(_Float16, (unsigned short)(v >> 16));
}
__device__ __forceinline__ unsigned int f2h(float f) {
    return (unsigned int)__builtin_bit_cast(unsigned short, (_Float16)f);
}

__global__ void cast_kernel(const float* __restrict__ x, ushort_t* __restrict__ xh, int n4) {
    int i = blockIdx.x * blockDim.x + threadIdx.x;
    if (i < n4) {
        float4 v = ((const float4*)x)[i];
        uint2 p;
        p.x = f2h(v.x) | (f2h(v.y) << 16);
        p.y = f2h(v.z) | (f2h(v.w) << 16);
        ((uint2*)xh)[i] = p;
    }
}

// W[l][k][n] f32 -> Wt_hi/Wt_lo[l][n][k] bf16 (transposed, hi+lo split)
__global__ void prep_w_kernel(const float* __restrict__ W,
                              ushort_t* __restrict__ whi, ushort_t* __restrict__ wlo,
                              int total) {
    int i = blockIdx.x * blockDim.x + threadIdx.x;
    if (i >= total) return;
    int l = i >> 12, r = i & 4095;
    int n = r >> 6, k = r & 63;
    float w = W[l * 4096 + k * 64 + n];
    __bf16 h = (__bf16)w;
    float rem = w - (float)h;
    __bf16 lo = (__bf16)rem;
    whi[i] = __builtin_bit_cast(ushort_t, h);
    wlo[i] = __builtin_bit_cast(ushort_t, lo);
}

// A: per-block LDS bucket histogram -> cnt2d[blk][bkt] (dense, no global atomics)
__global__ __launch_bounds__(256) void bucket_count_kernel(
        const int* __restrict__ dst, int* __restrict__ cnt2d,
        int E, int nbkt, int ebpb) {
    __shared__ int lcnt[256];
    int t = threadIdx.x;
    lcnt[t] = 0;
    __syncthreads();
    int base = blockIdx.x * ebpb;
    int end = min(base + ebpb, E);
    for (int i = base + t; i < end; i += 256)
        atomicAdd(&lcnt[dst[i] >> 9], 1);
    __syncthreads();
    if (t < nbkt) cnt2d[(size_t)blockIdx.x * nbkt + t] = lcnt[t];
}

// B1: block b scans column b of cnt2d over NBLK chunks -> blkoff[b][blk], btot[b]
__global__ __launch_bounds__(256) void colscan_kernel(
        const int* __restrict__ cnt2d, int* __restrict__ blkoff,
        int* __restrict__ btot, int nbkt) {
    __shared__ int sh[256];
    int b = blockIdx.x, t = threadIdx.x;
    int i0 = 2 * t, i1 = 2 * t + 1;
    int v0 = cnt2d[(size_t)i0 * nbkt + b];
    int v1 = cnt2d[(size_t)i1 * nbkt + b];
    int pair = v0 + v1;
    sh[t] = pair;
    __syncthreads();
    for (int off = 1; off < 256; off <<= 1) {
        int u = (t >= off) ? sh[t - off] : 0;
        __syncthreads();
        sh[t] += u;
        __syncthreads();
    }
    int ex = sh[t] - pair;
    blkoff[(size_t)b * NBLK + i0] = ex;
    blkoff[(size_t)b * NBLK + i1] = ex + v0;
    if (t == 255) btot[b] = sh[255];
}

// B2: scan btot[nbkt] -> bbase[nbkt+1]; also offsets[N]=E safety.
__global__ __launch_bounds__(256) void bucket_base_kernel(
        const int* __restrict__ btot, int* __restrict__ bbase,
        int* __restrict__ offsets, int nbkt, int N, int E) {
    __shared__ int sh[256];
    int t = threadIdx.x;
    int v = (t < nbkt) ? btot[t] : 0;
    sh[t] = v;
    __syncthreads();
    for (int off = 1; off < 256; off <<= 1) {
        int u = (t >= off) ? sh[t - off] : 0;
        __syncthreads();
        sh[t] += u;
        __syncthreads();
    }
    if (t < nbkt) bbase[t] = sh[t] - v;
    if (t == 0) { bbase[nbkt] = E; offsets[N] = E; }
}

// C: scatter edges into bucket regions as packed (src<<9)|d_local.
// Slot = bbase[b] + blkoff[b][blk] + LDS-local rank. LDS atomics only.
__global__ __launch_bounds__(256) void bucket_scatter_kernel(
        const int* __restrict__ src, const int* __restrict__ dst,
        const int* __restrict__ bbase, const int* __restrict__ blkoff,
        unsigned int* __restrict__ bkt, int E, int nbkt, int ebpb) {
    __shared__ int lbase[256];
    __shared__ int lrank[256];
    int t = threadIdx.x;
    if (t < nbkt) lbase[t] = bbase[t] + blkoff[(size_t)t * NBLK + blockIdx.x];
    lrank[t] = 0;
    __syncthreads();
    int base = blockIdx.x * ebpb;
    int end = min(base + ebpb, E);
    for (int i = base + t; i < end; i += 256) {
        int d = dst[i];
        int b = d >> 9;
        int r = atomicAdd(&lrank[b], 1);
        bkt[lbase[b] + r] = ((unsigned int)src[i] << 9) | (unsigned int)(d & (BS - 1));
    }
}

// D: block b = bucket b. LDS hist over 512 nodes -> LDS scan -> offsets (global
// offsets[d] = bbase[b] + lds_prefix, no global scan) -> csr fill (LDS rank).
__global__ __launch_bounds__(256) void csr_build_kernel(
        const unsigned int* __restrict__ bkt, const int* __restrict__ bbase,
        int* __restrict__ offsets, int* __restrict__ csr, int N, int nbkt) {
    __shared__ int cnt[BS];
    __shared__ int rank[BS];
    __shared__ int sh[256];
    int b = blockIdx.x, t = threadIdx.x;
    cnt[t] = 0; cnt[t + 256] = 0;
    rank[t] = 0; rank[t + 256] = 0;
    __syncthreads();
    int base = bbase[b], end = bbase[b + 1];
    for (int i = base + t; i < end; i += 256)
        atomicAdd(&cnt[bkt[i] & (BS - 1)], 1);
    __syncthreads();
    // exclusive scan over 512 counters (pair method)
    int i0 = 2 * t, i1 = 2 * t + 1;
    int v0 = cnt[i0], v1 = cnt[i1];
    int pair = v0 + v1;
    sh[t] = pair;
    __syncthreads();
    for (int off = 1; off < 256; off <<= 1) {
        int u = (t >= off) ? sh[t - off] : 0;
        __syncthreads();
        sh[t] += u;
        __syncthreads();
    }
    int ex = sh[t] - pair;
    __syncthreads();
    cnt[i0] = ex;           // cnt now holds exclusive prefix
    cnt[i1] = ex + v0;
    __syncthreads();
    int d0 = (b << 9) + i0;
    if (d0 <= N) offsets[d0] = base + cnt[i0];
    int d1 = (b << 9) + i1;
    if (d1 <= N) offsets[d1] = base + cnt[i1];
    for (int i = base + t; i < end; i += 256) {
        unsigned int v = bkt[i];
        int dl = v & (BS - 1);
        int r = atomicAdd(&rank[dl], 1);
        csr[base + cnt[dl] + r] = (int)(v >> 9);
    }
}

// One wave per node. Preload <=64 csr indices (one coalesced load), broadcast
// with shfl; unroll-8 gather loop -> ~8 independent 128B row loads in flight.
__global__ __launch_bounds__(256) void agg_kernel(
        const ushort_t* __restrict__ hin, float* __restrict__ agg,
        const int* __restrict__ offsets, const int* __restrict__ csr,
        const float* __restrict__ eps_arr, int layer, int N) {
    int lane = threadIdx.x & 63;
    int wave = threadIdx.x >> 6;
    int n = blockIdx.x * 4 + wave;
    if (n >= N) return;
    float eps1 = 1.0f + eps_arr[layer];

    int g  = lane >> 4;    // edge group 0..3
    int sl = lane & 15;    // uint2 slot within row (dims 4sl..4sl+3)

    int e0 = offsets[n], e1 = offsets[n + 1];
    int deg = e1 - e0;
    int idx = (lane < deg) ? csr[e0 + lane] : 0;
    int dcap = min(deg, 64);

    float ax = 0.f, ay = 0.f, az = 0.f, aw = 0.f;
    #pragma unroll 8
    for (int j = g; j < dcap; j += 4) {
        int s = __shfl(idx, j, 64);
        uint2 v = ((const uint2*)(hin + (size_t)s * 64))[sl];
        ax += h2f_lo(v.x); ay += h2f_hi(v.x); az += h2f_lo(v.y); aw += h2f_hi(v.y);
    }
    for (int e = e0 + 64 + g; e < e1; e += 4) {   // rare tail: deg > 64
        int s = csr[e];
        uint2 v = ((const uint2*)(hin + (size_t)s * 64))[sl];
        ax += h2f_lo(v.x); ay += h2f_hi(v.x); az += h2f_lo(v.y); aw += h2f_hi(v.y);
    }

    ax += __shfl_xor(ax, 16, 64); ax += __shfl_xor(ax, 32, 64);
    ay += __shfl_xor(ay, 16, 64); ay += __shfl_xor(ay, 32, 64);
    az += __shfl_xor(az, 16, 64); az += __shfl_xor(az, 32, 64);
    aw += __shfl_xor(aw, 16, 64); aw += __shfl_xor(aw, 32, 64);

    uint2 self = ((const uint2*)(hin + (size_t)n * 64))[sl];
    ax = fmaf(eps1, h2f_lo(self.x), ax);
    ay = fmaf(eps1, h2f_hi(self.x), ay);
    az = fmaf(eps1, h2f_lo(self.y), az);
    aw = fmaf(eps1, h2f_hi(self.y), aw);

    if (g == 0) {
        float4 v; v.x = ax; v.y = ay; v.z = az; v.w = aw;
        ((float4*)(agg + (size_t)n * 64))[sl] = v;
    }
}

// h_out[node][d] = relu(b[d] + sum_k agg[node][k] * W[k][d]) via MFMA.
// A = Wt (hi/lo bf16), B = agg rows (hi/lo bf16 in-register), 3-MFMA split.
__global__ __launch_bounds__(256) void gemm_kernel(
        const float* __restrict__ agg, ushort_t* __restrict__ hout,
        const ushort_t* __restrict__ wt_hi, const ushort_t* __restrict__ wt_lo,
        const float* __restrict__ gin_b, int layer, int N) {
    int wave = threadIdx.x >> 6;
    int lane = threadIdx.x & 63;
    int tile = blockIdx.x * 4 + wave;
    if (tile * 16 >= N) return;
    int c = lane & 15;
    int q = lane >> 4;
    int node = tile * 16 + c;
    int lnode = min(node, N - 1);

    const ushort_t* Whi = wt_hi + layer * 4096;
    const ushort_t* Wlo = wt_lo + layer * 4096;
    const float*    bl  = gin_b + layer * 64;

    v8bf bhi[2], blo2[2];
    #pragma unroll
    for (int kt = 0; kt < 2; ++kt) {
        const float* p = agg + (size_t)lnode * 64 + kt * 32 + q * 8;
        float4 f0 = ((const float4*)p)[0];
        float4 f1 = ((const float4*)p)[1];
        float xs[8] = {f0.x, f0.y, f0.z, f0.w, f1.x, f1.y, f1.z, f1.w};
        #pragma unroll
        for (int j = 0; j < 8; ++j) {
            __bf16 h = (__bf16)xs[j];
            bhi[kt][j] = h;
            blo2[kt][j] = (__bf16)(xs[j] - (float)h);
        }
    }

    #pragma unroll
    for (int mt = 0; mt < 4; ++mt) {
        v4f acc = {0.f, 0.f, 0.f, 0.f};
        #pragma unroll
        for (int kt = 0; kt < 2; ++kt) {
            int dim = mt * 16 + c;
            size_t off = (size_t)dim * 64 + kt * 32 + q * 8;
            v8bf ah = __builtin_bit_cast(v8bf, *(const uint4*)(Whi + off));
            v8bf al = __builtin_bit_cast(v8bf, *(const uint4*)(Wlo + off));
            acc = __builtin_amdgcn_mfma_f32_16x16x32_bf16(ah, bhi[kt],  acc, 0, 0, 0);
            acc = __builtin_amdgcn_mfma_f32_16x16x32_bf16(ah, blo2[kt], acc, 0, 0, 0);
            acc = __builtin_amdgcn_mfma_f32_16x16x32_bf16(al, bhi[kt],  acc, 0, 0, 0);
        }
        float4 bv = ((const float4*)(bl + mt * 16))[q];
        float o0 = fmaxf(acc[0] + bv.x, 0.f);
        float o1 = fmaxf(acc[1] + bv.y, 0.f);
        float o2 = fmaxf(acc[2] + bv.z, 0.f);
        float o3 = fmaxf(acc[3] + bv.w, 0.f);
        uint2 pk;
        pk.x = f2h(o0) | (f2h(o1) << 16);
        pk.y = f2h(o2) | (f2h(o3) << 16);
        if (node < N)
            *(uint2*)(hout + (size_t)node * 64 + mt * 16 + q * 4) = pk;
    }
}

// 256 graphs x SPLIT splits; 192 threads (t = l*64+d); f16 H, f32 accumulate.
__global__ __launch_bounds__(192) void readout_kernel(
        const ushort_t* __restrict__ H, const int* __restrict__ gids,
        float* __restrict__ g, int N) {
    int graph = blockIdx.x / SPLIT;
    int sp    = blockIdx.x % SPLIT;
    int lo = 0, hi = N;
    while (lo < hi) { int mid = (lo + hi) >> 1; if (gids[mid] < graph) lo = mid + 1; else hi = mid; }
    int start = lo;
    int lo2 = start, hi2 = N;
    while (lo2 < hi2) { int mid = (lo2 + hi2) >> 1; if (gids[mid] < graph + 1) lo2 = mid + 1; else hi2 = mid; }
    int end = lo2;
    int cnt = end - start;
    if (cnt <= 0) return;
    int per = (cnt + SPLIT - 1) / SPLIT;
    int cs = start + sp * per;
    int ce = min(cs + per, end);
    if (cs >= ce) return;

    int t = threadIdx.x;
    int l = t >> 6, d = t & 63;
    const ushort_t* Hl = H + (size_t)l * N * 64;
    float acc = 0.0f;
    for (int n = cs; n < ce; ++n)
        acc += (float)__builtin_bit_cast(_Float16, Hl[(size_t)n * 64 + d]);
    atomicAdd(&g[graph * 192 + t], acc);
}

__global__ __launch_bounds__(192) void mlp_kernel(
        const float* __restrict__ g,
        const float* __restrict__ W1, const float* __restrict__ b1,
        const float* __restrict__ W2, const float* __restrict__ b2,
        float* __restrict__ out) {
    __shared__ float gr[192];
    __shared__ float hid[128];
    int graph = blockIdx.x;
    int t = threadIdx.x;
    gr[t] = g[graph * 192 + t];
    __syncthreads();
    if (t < 128) {
        float a = b1[t];
        for (int k = 0; k < 192; ++k) a = fmaf(gr[k], W1[k * 128 + t], a);
        hid[t] = fmaxf(a, 0.0f);
    }
    __syncthreads();
    if (t < 32) {
        float a = b2[t];
        for (int k = 0; k < 128; ++k) a = fmaf(hid[k], W2[k * 32 + t], a);
        out[graph * 32 + t] = a;
    }
}

extern "C" void kernel_launch(void* const* d_in, const int* in_sizes, int n_in,
                              void* d_out, int out_size, void* d_ws, size_t ws_size,
                              hipStream_t stream) {
    const float* x     = (const float*)d_in[0];
    const float* gin_W = (const float*)d_in[1];
    const float* gin_b = (const float*)d_in[2];
    const float* eps   = (const float*)d_in[3];
    const float* r_W1  = (const float*)d_in[4];
    const float* r_b1  = (const float*)d_in[5];
    const float* r_W2  = (const float*)d_in[6];
    const float* r_b2  = (const float*)d_in[7];
    const int*   src   = (const int*)d_in[8];
    const int*   dst   = (const int*)d_in[9];
    const int*   gids  = (const int*)d_in[10];

    int N = in_sizes[0] / 64;       // 100000
    int E = in_sizes[8];            // 1200000
    int B = out_size / 32;          // 256

    int nbkt = (N + BS - 1) / BS;   // 196 (must be <= 256)
    int ebpb = (E + NBLK - 1) / NBLK;

    // workspace layout (4B words):
    //   g[B*192]                               <- zeroed
    //   cnt2d[NBLK*nbkt] | blkoff[nbkt*NBLK] | btot[nbkt] | bbase[nbkt+1]
    //   offsets[N+1] | bkt[E] | csr[E] | pad
    //   xh[N*64 f16] | H[3*N*64 f16] | whi[3*4096] | wlo[3*4096] | pad | agg[N*64 f32]
    int* ws       = (int*)d_ws;
    float* g      = (float*)ws;
    int* cnt2d    = ws + (size_t)B * 192;
    int* blkoff   = cnt2d + (size_t)NBLK * nbkt;
    int* btot     = blkoff + (size_t)nbkt * NBLK;
    int* bbase    = btot + nbkt;
    int* offsets  = bbase + (nbkt + 1);
    unsigned int* bkt = (unsigned int*)(offsets + (N + 1));
    int* csr      = (int*)(bkt + E);
    size_t w      = (size_t)(csr + E - ws);
    w = (w + 15) & ~(size_t)15;     // 64B align
    ushort_t* xh  = (ushort_t*)(ws + w);
    ushort_t* H   = xh + (size_t)N * 64;
    ushort_t* whi = H + 3 * (size_t)N * 64;
    ushort_t* wlo = whi + 3 * 4096;
    size_t w2     = ((size_t)((int*)(wlo + 3 * 4096) - ws) + 15) & ~(size_t)15;
    float* agg    = (float*)(ws + w2);

    hipMemsetAsync(d_ws, 0, (size_t)B * 192 * sizeof(float), stream);

    cast_kernel<<<(N * 64 / 4 + 255) / 256, 256, 0, stream>>>(x, xh, N * 64 / 4);
    prep_w_kernel<<<(3 * 4096 + 255) / 256, 256, 0, stream>>>(gin_W, whi, wlo, 3 * 4096);
    bucket_count_kernel<<<NBLK, 256, 0, stream>>>(dst, cnt2d, E, nbkt, ebpb);
    colscan_kernel<<<nbkt, 256, 0, stream>>>(cnt2d, blkoff, btot, nbkt);
    bucket_base_kernel<<<1, 256, 0, stream>>>(btot, bbase, offsets, nbkt, N, E);
    bucket_scatter_kernel<<<NBLK, 256, 0, stream>>>(src, dst, bbase, blkoff, bkt, E, nbkt, ebpb);
    csr_build_kernel<<<nbkt, 256, 0, stream>>>(bkt, bbase, offsets, csr, N, nbkt);

    int nbk = (N + 3) / 4;                       // agg: wave per node, 4/block
    int gbk = ((N + 15) / 16 + 3) / 4;           // gemm: wave per 16 nodes, 4/block
    ushort_t* H0 = H;
    ushort_t* H1 = H + (size_t)N * 64;
    ushort_t* H2 = H + 2 * (size_t)N * 64;

    agg_kernel<<<nbk, 256, 0, stream>>>(xh, agg, offsets, csr, eps, 0, N);
    gemm_kernel<<<gbk, 256, 0, stream>>>(agg, H0, whi, wlo, gin_b, 0, N);
    agg_kernel<<<nbk, 256, 0, stream>>>(H0, agg, offsets, csr, eps, 1, N);
    gemm_kernel<<<gbk, 256, 0, stream>>>(agg, H1, whi, wlo, gin_b, 1, N);
    agg_kernel<<<nbk, 256, 0, stream>>>(H1, agg, offsets, csr, eps, 2, N);
    gemm_kernel<<<gbk, 256, 0, stream>>>(agg, H2, whi, wlo, gin_b, 2, N);

    readout_kernel<<<B * SPLIT, 192, 0, stream>>>(H, gids, g, N);
    mlp_kernel<<<B, 192, 0, stream>>>(g, r_W1, r_b1, r_W2, r_b2, (float*)d_out);
}

// Round 10
// 326.087 us; speedup vs baseline: 1.2885x; 1.1465x over previous
//
#include <hip/hip_runtime.h>

// GIN: 3 layers of {agg = scatter_sum(h[src] -> dst); h = relu(((1+eps)h + agg) @ W + b)}
// then per-graph segment-sum readout (graph_ids sorted) -> 2-layer MLP.
//
// R10: (a) fused layer kernel: wave-autonomous 16-node tile. 4 gather passes
//      (4 nodes/pass, 16-lane group owns a full 128B row -> no reduce), agg
//      rows in wave-private LDS (4KB, no __syncthreads), then R5's verified
//      MFMA epilogue (bf16 hi/lo split) from LDS. Removes 50MB/layer agg-f32
//      round trip + 3 dispatches. (b) readout -> dense gpart partials (no
//      global atomics; R8 measured ~32B fabric write per atomic), summed in
//      mlp. No memset needed.
// R9: atomic-free bucketed CSR build. R7: f16 H. R5: MFMA gemm. R3: par scan.
// agg FETCH floor: 8 XCDs x 12.8MB compulsory (uniform random src) ~= 102MB.

#define SPLIT 16
#define NBLK 512     // edge chunks for bucket build
#define BS 512       // nodes per bucket (pow2; d_local = d & 511, bucket = d >> 9)

typedef unsigned short ushort_t;
typedef __bf16 v8bf __attribute__((ext_vector_type(8)));
typedef float v4f __attribute__((ext_vector_type(4)));

__device__ __forceinline__ float h2f_lo(unsigned int v) {
    return (float)__builtin_bit_cast(_Float16, (unsigned short)(v & 0xffffu));
}
__device__ __forceinline__ float h2f_hi(unsigned int v) {
    return (float)__builtin_bit_cast(_Float16, (unsigned short)(v >> 16));
}
__device__ __forceinline__ unsigned int f2h(float f) {
    return (unsigned int)__builtin_bit_cast(unsigned short, (_Float16)f);
}

__global__ void cast_kernel(const float* __restrict__ x, ushort_t* __restrict__ xh, int n4) {
    int i = blockIdx.x * blockDim.x + threadIdx.x;
    if (i < n4) {
        float4 v = ((const float4*)x)[i];
        uint2 p;
        p.x = f2h(v.x) | (f2h(v.y) << 16);
        p.y = f2h(v.z) | (f2h(v.w) << 16);
        ((uint2*)xh)[i] = p;
    }
}

// W[l][k][n] f32 -> Wt_hi/Wt_lo[l][n][k] bf16 (transposed, hi+lo split)
__global__ void prep_w_kernel(const float* __restrict__ W,
                              ushort_t* __restrict__ whi, ushort_t* __restrict__ wlo,
                              int total) {
    int i = blockIdx.x * blockDim.x + threadIdx.x;
    if (i >= total) return;
    int l = i >> 12, r = i & 4095;
    int n = r >> 6, k = r & 63;
    float w = W[l * 4096 + k * 64 + n];
    __bf16 h = (__bf16)w;
    float rem = w - (float)h;
    __bf16 lo = (__bf16)rem;
    whi[i] = __builtin_bit_cast(ushort_t, h);
    wlo[i] = __builtin_bit_cast(ushort_t, lo);
}

// A: per-block LDS bucket histogram -> cnt2d[blk][bkt] (dense, no global atomics)
__global__ __launch_bounds__(256) void bucket_count_kernel(
        const int* __restrict__ dst, int* __restrict__ cnt2d,
        int E, int nbkt, int ebpb) {
    __shared__ int lcnt[256];
    int t = threadIdx.x;
    lcnt[t] = 0;
    __syncthreads();
    int base = blockIdx.x * ebpb;
    int end = min(base + ebpb, E);
    for (int i = base + t; i < end; i += 256)
        atomicAdd(&lcnt[dst[i] >> 9], 1);
    __syncthreads();
    if (t < nbkt) cnt2d[(size_t)blockIdx.x * nbkt + t] = lcnt[t];
}

// B1: block b scans column b of cnt2d over NBLK chunks -> blkoff[b][blk], btot[b]
__global__ __launch_bounds__(256) void colscan_kernel(
        const int* __restrict__ cnt2d, int* __restrict__ blkoff,
        int* __restrict__ btot, int nbkt) {
    __shared__ int sh[256];
    int b = blockIdx.x, t = threadIdx.x;
    int i0 = 2 * t, i1 = 2 * t + 1;
    int v0 = cnt2d[(size_t)i0 * nbkt + b];
    int v1 = cnt2d[(size_t)i1 * nbkt + b];
    int pair = v0 + v1;
    sh[t] = pair;
    __syncthreads();
    for (int off = 1; off < 256; off <<= 1) {
        int u = (t >= off) ? sh[t - off] : 0;
        __syncthreads();
        sh[t] += u;
        __syncthreads();
    }
    int ex = sh[t] - pair;
    blkoff[(size_t)b * NBLK + i0] = ex;
    blkoff[(size_t)b * NBLK + i1] = ex + v0;
    if (t == 255) btot[b] = sh[255];
}

// B2: scan btot[nbkt] -> bbase[nbkt+1]; also offsets[N]=E safety.
__global__ __launch_bounds__(256) void bucket_base_kernel(
        const int* __restrict__ btot, int* __restrict__ bbase,
        int* __restrict__ offsets, int nbkt, int N, int E) {
    __shared__ int sh[256];
    int t = threadIdx.x;
    int v = (t < nbkt) ? btot[t] : 0;
    sh[t] = v;
    __syncthreads();
    for (int off = 1; off < 256; off <<= 1) {
        int u = (t >= off) ? sh[t - off] : 0;
        __syncthreads();
        sh[t] += u;
        __syncthreads();
    }
    if (t < nbkt) bbase[t] = sh[t] - v;
    if (t == 0) { bbase[nbkt] = E; offsets[N] = E; }
}

// C: scatter edges into bucket regions as packed (src<<9)|d_local.
__global__ __launch_bounds__(256) void bucket_scatter_kernel(
        const int* __restrict__ src, const int* __restrict__ dst,
        const int* __restrict__ bbase, const int* __restrict__ blkoff,
        unsigned int* __restrict__ bkt, int E, int nbkt, int ebpb) {
    __shared__ int lbase[256];
    __shared__ int lrank[256];
    int t = threadIdx.x;
    if (t < nbkt) lbase[t] = bbase[t] + blkoff[(size_t)t * NBLK + blockIdx.x];
    lrank[t] = 0;
    __syncthreads();
    int base = blockIdx.x * ebpb;
    int end = min(base + ebpb, E);
    for (int i = base + t; i < end; i += 256) {
        int d = dst[i];
        int b = d >> 9;
        int r = atomicAdd(&lrank[b], 1);
        bkt[lbase[b] + r] = ((unsigned int)src[i] << 9) | (unsigned int)(d & (BS - 1));
    }
}

// D: block b = bucket b. LDS hist + scan -> offsets + csr (LDS atomics only).
__global__ __launch_bounds__(256) void csr_build_kernel(
        const unsigned int* __restrict__ bkt, const int* __restrict__ bbase,
        int* __restrict__ offsets, int* __restrict__ csr, int N, int nbkt) {
    __shared__ int cnt[BS];
    __shared__ int rank[BS];
    __shared__ int sh[256];
    int b = blockIdx.x, t = threadIdx.x;
    cnt[t] = 0; cnt[t + 256] = 0;
    rank[t] = 0; rank[t + 256] = 0;
    __syncthreads();
    int base = bbase[b], end = bbase[b + 1];
    for (int i = base + t; i < end; i += 256)
        atomicAdd(&cnt[bkt[i] & (BS - 1)], 1);
    __syncthreads();
    int i0 = 2 * t, i1 = 2 * t + 1;
    int v0 = cnt[i0], v1 = cnt[i1];
    int pair = v0 + v1;
    sh[t] = pair;
    __syncthreads();
    for (int off = 1; off < 256; off <<= 1) {
        int u = (t >= off) ? sh[t - off] : 0;
        __syncthreads();
        sh[t] += u;
        __syncthreads();
    }
    int ex = sh[t] - pair;
    __syncthreads();
    cnt[i0] = ex;
    cnt[i1] = ex + v0;
    __syncthreads();
    int d0 = (b << 9) + i0;
    if (d0 <= N) offsets[d0] = base + cnt[i0];
    int d1 = (b << 9) + i1;
    if (d1 <= N) offsets[d1] = base + cnt[i1];
    for (int i = base + t; i < end; i += 256) {
        unsigned int v = bkt[i];
        int dl = v & (BS - 1);
        int r = atomicAdd(&rank[dl], 1);
        csr[base + cnt[dl] + r] = (int)(v >> 9);
    }
}

// Fused GIN layer: wave-autonomous 16-node tile, 4 waves/block (independent).
// Gather: 4 passes x 4 nodes; lane = nq*16+sl; 16-lane group owns node's full
// 128B row (lane sl holds dims 4sl..4sl+3, f32 acc) -> wave-private LDS.
// GEMM: R5's verified MFMA epilogue (A=Wt hi/lo, B=agg rows hi/lo, 3-MFMA).
__global__ __launch_bounds__(256) void layer_kernel(
        const ushort_t* __restrict__ hin, ushort_t* __restrict__ hout,
        const int* __restrict__ offsets, const int* __restrict__ csr,
        const ushort_t* __restrict__ wt_hi, const ushort_t* __restrict__ wt_lo,
        const float* __restrict__ gin_b, const float* __restrict__ eps_arr,
        int layer, int N) {
    __shared__ float rows[4 * 16 * 64];   // 16KB: 4 waves x 16 nodes x 64 f32
    int t = threadIdx.x;
    int wv = t >> 6, lane = t & 63;
    int tile = blockIdx.x * 4 + wv;
    if (tile * 16 >= N) return;           // waves independent: safe early-out
    float* myrows = rows + wv * 16 * 64;
    float eps1 = 1.0f + eps_arr[layer];

    int nq = lane >> 4;    // node within pass
    int sl = lane & 15;    // uint2 slot (dims 4sl..4sl+3)

    #pragma unroll
    for (int p = 0; p < 4; ++p) {
        int node = tile * 16 + p * 4 + nq;
        float ax = 0.f, ay = 0.f, az = 0.f, aw = 0.f;
        if (node < N) {
            int e0 = offsets[node], e1 = offsets[node + 1];
            #pragma unroll 4
            for (int e = e0; e < e1; ++e) {
                int s = csr[e];    // group-uniform (broadcast within 16 lanes)
                uint2 v = ((const uint2*)(hin + (size_t)s * 64))[sl];
                ax += h2f_lo(v.x); ay += h2f_hi(v.x);
                az += h2f_lo(v.y); aw += h2f_hi(v.y);
            }
            uint2 self = ((const uint2*)(hin + (size_t)node * 64))[sl];
            ax = fmaf(eps1, h2f_lo(self.x), ax);
            ay = fmaf(eps1, h2f_hi(self.x), ay);
            az = fmaf(eps1, h2f_lo(self.y), az);
            aw = fmaf(eps1, h2f_hi(self.y), aw);
        }
        float4 r4; r4.x = ax; r4.y = ay; r4.z = az; r4.w = aw;
        *(float4*)&myrows[(p * 4 + nq) * 64 + sl * 4] = r4;
    }
    // intra-wave LDS ordering: compiler emits lgkmcnt before reads; no barrier.

    int c = lane & 15;     // node within tile / n-index
    int q = lane >> 4;     // quad
    int node16 = tile * 16 + c;

    const ushort_t* Whi = wt_hi + layer * 4096;
    const ushort_t* Wlo = wt_lo + layer * 4096;
    const float*    bl  = gin_b + layer * 64;

    v8bf bhi[2], blo2[2];
    #pragma unroll
    for (int kt = 0; kt < 2; ++kt) {
        float4 f0 = *(float4*)&myrows[c * 64 + kt * 32 + q * 8];
        float4 f1 = *(float4*)&myrows[c * 64 + kt * 32 + q * 8 + 4];
        float xs[8] = {f0.x, f0.y, f0.z, f0.w, f1.x, f1.y, f1.z, f1.w};
        #pragma unroll
        for (int j = 0; j < 8; ++j) {
            __bf16 h = (__bf16)xs[j];
            bhi[kt][j] = h;
            blo2[kt][j] = (__bf16)(xs[j] - (float)h);
        }
    }

    #pragma unroll
    for (int mt = 0; mt < 4; ++mt) {
        v4f acc = {0.f, 0.f, 0.f, 0.f};
        #pragma unroll
        for (int kt = 0; kt < 2; ++kt) {
            int dim = mt * 16 + c;
            size_t off = (size_t)dim * 64 + kt * 32 + q * 8;
            v8bf ah = __builtin_bit_cast(v8bf, *(const uint4*)(Whi + off));
            v8bf al = __builtin_bit_cast(v8bf, *(const uint4*)(Wlo + off));
            acc = __builtin_amdgcn_mfma_f32_16x16x32_bf16(ah, bhi[kt],  acc, 0, 0, 0);
            acc = __builtin_amdgcn_mfma_f32_16x16x32_bf16(ah, blo2[kt], acc, 0, 0, 0);
            acc = __builtin_amdgcn_mfma_f32_16x16x32_bf16(al, bhi[kt],  acc, 0, 0, 0);
        }
        float4 bv = ((const float4*)(bl + mt * 16))[q];
        float o0 = fmaxf(acc[0] + bv.x, 0.f);
        float o1 = fmaxf(acc[1] + bv.y, 0.f);
        float o2 = fmaxf(acc[2] + bv.z, 0.f);
        float o3 = fmaxf(acc[3] + bv.w, 0.f);
        uint2 pk;
        pk.x = f2h(o0) | (f2h(o1) << 16);
        pk.y = f2h(o2) | (f2h(o3) << 16);
        if (node16 < N)
            *(uint2*)(hout + (size_t)node16 * 64 + mt * 16 + q * 4) = pk;
    }
}

// Phase 1: dense partials, no atomics. gpart[(graph*SPLIT+sp)*192 + t].
__global__ __launch_bounds__(192) void readout_part_kernel(
        const ushort_t* __restrict__ H, const int* __restrict__ gids,
        float* __restrict__ gpart, int N) {
    int graph = blockIdx.x / SPLIT;
    int sp    = blockIdx.x % SPLIT;
    int lo = 0, hi = N;
    while (lo < hi) { int mid = (lo + hi) >> 1; if (gids[mid] < graph) lo = mid + 1; else hi = mid; }
    int start = lo;
    int lo2 = start, hi2 = N;
    while (lo2 < hi2) { int mid = (lo2 + hi2) >> 1; if (gids[mid] < graph + 1) lo2 = mid + 1; else hi2 = mid; }
    int end = lo2;
    int t = threadIdx.x;            // 0..191
    int l = t >> 6, d = t & 63;
    float acc = 0.0f;
    int cnt = end - start;
    if (cnt > 0) {
        int per = (cnt + SPLIT - 1) / SPLIT;
        int cs = start + sp * per;
        int ce = min(cs + per, end);
        const ushort_t* Hl = H + (size_t)l * N * 64;
        for (int n = cs; n < ce; ++n)
            acc += (float)__builtin_bit_cast(_Float16, Hl[(size_t)n * 64 + d]);
    }
    gpart[(size_t)(graph * SPLIT + sp) * 192 + t] = acc;   // unconditional
}

// Phase 2 fused with MLP: sum 16 partials -> gr, then 2-layer MLP.
__global__ __launch_bounds__(192) void mlp_kernel(
        const float* __restrict__ gpart,
        const float* __restrict__ W1, const float* __restrict__ b1,
        const float* __restrict__ W2, const float* __restrict__ b2,
        float* __restrict__ out) {
    __shared__ float gr[192];
    __shared__ float hid[128];
    int graph = blockIdx.x;
    int t = threadIdx.x;
    float a = 0.f;
    #pragma unroll
    for (int sp = 0; sp < SPLIT; ++sp)
        a += gpart[(size_t)(graph * SPLIT + sp) * 192 + t];
    gr[t] = a;
    __syncthreads();
    if (t < 128) {
        float s = b1[t];
        for (int k = 0; k < 192; ++k) s = fmaf(gr[k], W1[k * 128 + t], s);
        hid[t] = fmaxf(s, 0.0f);
    }
    __syncthreads();
    if (t < 32) {
        float s = b2[t];
        for (int k = 0; k < 128; ++k) s = fmaf(hid[k], W2[k * 32 + t], s);
        out[graph * 32 + t] = s;
    }
}

extern "C" void kernel_launch(void* const* d_in, const int* in_sizes, int n_in,
                              void* d_out, int out_size, void* d_ws, size_t ws_size,
                              hipStream_t stream) {
    const float* x     = (const float*)d_in[0];
    const float* gin_W = (const float*)d_in[1];
    const float* gin_b = (const float*)d_in[2];
    const float* eps   = (const float*)d_in[3];
    const float* r_W1  = (const float*)d_in[4];
    const float* r_b1  = (const float*)d_in[5];
    const float* r_W2  = (const float*)d_in[6];
    const float* r_b2  = (const float*)d_in[7];
    const int*   src   = (const int*)d_in[8];
    const int*   dst   = (const int*)d_in[9];
    const int*   gids  = (const int*)d_in[10];

    int N = in_sizes[0] / 64;       // 100000
    int E = in_sizes[8];            // 1200000
    int B = out_size / 32;          // 256

    int nbkt = (N + BS - 1) / BS;   // 196 (<= 256)
    int ebpb = (E + NBLK - 1) / NBLK;

    // workspace layout (4B words), all regions fully written before read:
    //   gpart[B*SPLIT*192]
    //   cnt2d[NBLK*nbkt] | blkoff[nbkt*NBLK] | btot[nbkt] | bbase[nbkt+1]
    //   offsets[N+1] | bkt[E] | csr[E] | pad
    //   xh[N*64 f16] | H[3*N*64 f16] | whi[3*4096] | wlo[3*4096]
    int* ws       = (int*)d_ws;
    float* gpart  = (float*)ws;
    int* cnt2d    = ws + (size_t)B * SPLIT * 192;
    int* blkoff   = cnt2d + (size_t)NBLK * nbkt;
    int* btot     = blkoff + (size_t)nbkt * NBLK;
    int* bbase    = btot + nbkt;
    int* offsets  = bbase + (nbkt + 1);
    unsigned int* bkt = (unsigned int*)(offsets + (N + 1));
    int* csr      = (int*)(bkt + E);
    size_t w      = (size_t)(csr + E - ws);
    w = (w + 15) & ~(size_t)15;     // 64B align
    ushort_t* xh  = (ushort_t*)(ws + w);
    ushort_t* H   = xh + (size_t)N * 64;
    ushort_t* whi = H + 3 * (size_t)N * 64;
    ushort_t* wlo = whi + 3 * 4096;

    cast_kernel<<<(N * 64 / 4 + 255) / 256, 256, 0, stream>>>(x, xh, N * 64 / 4);
    prep_w_kernel<<<(3 * 4096 + 255) / 256, 256, 0, stream>>>(gin_W, whi, wlo, 3 * 4096);
    bucket_count_kernel<<<NBLK, 256, 0, stream>>>(dst, cnt2d, E, nbkt, ebpb);
    colscan_kernel<<<nbkt, 256, 0, stream>>>(cnt2d, blkoff, btot, nbkt);
    bucket_base_kernel<<<1, 256, 0, stream>>>(btot, bbase, offsets, nbkt, N, E);
    bucket_scatter_kernel<<<NBLK, 256, 0, stream>>>(src, dst, bbase, blkoff, bkt, E, nbkt, ebpb);
    csr_build_kernel<<<nbkt, 256, 0, stream>>>(bkt, bbase, offsets, csr, N, nbkt);

    int lbk = (N + 63) / 64;        // 4 tiles (waves) of 16 nodes per block
    ushort_t* H0 = H;
    ushort_t* H1 = H + (size_t)N * 64;
    ushort_t* H2 = H + 2 * (size_t)N * 64;

    layer_kernel<<<lbk, 256, 0, stream>>>(xh, H0, offsets, csr, whi, wlo, gin_b, eps, 0, N);
    layer_kernel<<<lbk, 256, 0, stream>>>(H0, H1, offsets, csr, whi, wlo, gin_b, eps, 1, N);
    layer_kernel<<<lbk, 256, 0, stream>>>(H1, H2, offsets, csr, whi, wlo, gin_b, eps, 2, N);

    readout_part_kernel<<<B * SPLIT, 192, 0, stream>>>(H, gids, gpart, N);
    mlp_kernel<<<B, 192, 0, stream>>>(gpart, r_W1, r_b1, r_W2, r_b2, (float*)d_out);
}

// Round 11
// 323.387 us; speedup vs baseline: 1.2993x; 1.0083x over previous
//
#include <hip/hip_runtime.h>

// GIN: 3 layers of {agg = scatter_sum(h[src] -> dst); h = relu(((1+eps)h + agg) @ W + b)}
// then per-graph segment-sum readout (graph_ids sorted) -> 2-layer MLP.
//
// R11: layer gather re-armed with R9's preload idiom: each 16-lane group
//      preloads 32 csr indices (2 regs, coalesced), gather = shfl + row-load,
//      unroll 8 -> ~32 edges in flight/wave (R10 had ~4 load instrs deep and
//      ran 2.55 TB/s vs R9 agg's 3.19). Rare deg>32 tail loads csr directly.
// R10: fused layer (gather+MFMA, wave-autonomous 16-node tile, LDS staging,
//      no barrier) + atomic-free two-phase readout.
// R9: atomic-free bucketed CSR build. R7: f16 H. R5: MFMA bf16 hi/lo gemm.
// Gather fabric ceiling observed ~3.2 TB/s (random 128B rows); FETCH floor
// ~102 MB/layer (8 XCDs x compulsory ~12.8 MB).

#define SPLIT 16
#define NBLK 512     // edge chunks for bucket build
#define BS 512       // nodes per bucket (pow2; d_local = d & 511, bucket = d >> 9)

typedef unsigned short ushort_t;
typedef __bf16 v8bf __attribute__((ext_vector_type(8)));
typedef float v4f __attribute__((ext_vector_type(4)));

__device__ __forceinline__ float h2f_lo(unsigned int v) {
    return (float)__builtin_bit_cast(_Float16, (unsigned short)(v & 0xffffu));
}
__device__ __forceinline__ float h2f_hi(unsigned int v) {
    return (float)__builtin_bit_cast(_Float16, (unsigned short)(v >> 16));
}
__device__ __forceinline__ unsigned int f2h(float f) {
    return (unsigned int)__builtin_bit_cast(unsigned short, (_Float16)f);
}

__global__ void cast_kernel(const float* __restrict__ x, ushort_t* __restrict__ xh, int n4) {
    int i = blockIdx.x * blockDim.x + threadIdx.x;
    if (i < n4) {
        float4 v = ((const float4*)x)[i];
        uint2 p;
        p.x = f2h(v.x) | (f2h(v.y) << 16);
        p.y = f2h(v.z) | (f2h(v.w) << 16);
        ((uint2*)xh)[i] = p;
    }
}

// W[l][k][n] f32 -> Wt_hi/Wt_lo[l][n][k] bf16 (transposed, hi+lo split)
__global__ void prep_w_kernel(const float* __restrict__ W,
                              ushort_t* __restrict__ whi, ushort_t* __restrict__ wlo,
                              int total) {
    int i = blockIdx.x * blockDim.x + threadIdx.x;
    if (i >= total) return;
    int l = i >> 12, r = i & 4095;
    int n = r >> 6, k = r & 63;
    float w = W[l * 4096 + k * 64 + n];
    __bf16 h = (__bf16)w;
    float rem = w - (float)h;
    __bf16 lo = (__bf16)rem;
    whi[i] = __builtin_bit_cast(ushort_t, h);
    wlo[i] = __builtin_bit_cast(ushort_t, lo);
}

// A: per-block LDS bucket histogram -> cnt2d[blk][bkt]
__global__ __launch_bounds__(256) void bucket_count_kernel(
        const int* __restrict__ dst, int* __restrict__ cnt2d,
        int E, int nbkt, int ebpb) {
    __shared__ int lcnt[256];
    int t = threadIdx.x;
    lcnt[t] = 0;
    __syncthreads();
    int base = blockIdx.x * ebpb;
    int end = min(base + ebpb, E);
    for (int i = base + t; i < end; i += 256)
        atomicAdd(&lcnt[dst[i] >> 9], 1);
    __syncthreads();
    if (t < nbkt) cnt2d[(size_t)blockIdx.x * nbkt + t] = lcnt[t];
}

// B1: block b scans column b of cnt2d over NBLK chunks -> blkoff[b][blk], btot[b]
__global__ __launch_bounds__(256) void colscan_kernel(
        const int* __restrict__ cnt2d, int* __restrict__ blkoff,
        int* __restrict__ btot, int nbkt) {
    __shared__ int sh[256];
    int b = blockIdx.x, t = threadIdx.x;
    int i0 = 2 * t, i1 = 2 * t + 1;
    int v0 = cnt2d[(size_t)i0 * nbkt + b];
    int v1 = cnt2d[(size_t)i1 * nbkt + b];
    int pair = v0 + v1;
    sh[t] = pair;
    __syncthreads();
    for (int off = 1; off < 256; off <<= 1) {
        int u = (t >= off) ? sh[t - off] : 0;
        __syncthreads();
        sh[t] += u;
        __syncthreads();
    }
    int ex = sh[t] - pair;
    blkoff[(size_t)b * NBLK + i0] = ex;
    blkoff[(size_t)b * NBLK + i1] = ex + v0;
    if (t == 255) btot[b] = sh[255];
}

// B2: scan btot[nbkt] -> bbase[nbkt+1]; offsets[N]=E.
__global__ __launch_bounds__(256) void bucket_base_kernel(
        const int* __restrict__ btot, int* __restrict__ bbase,
        int* __restrict__ offsets, int nbkt, int N, int E) {
    __shared__ int sh[256];
    int t = threadIdx.x;
    int v = (t < nbkt) ? btot[t] : 0;
    sh[t] = v;
    __syncthreads();
    for (int off = 1; off < 256; off <<= 1) {
        int u = (t >= off) ? sh[t - off] : 0;
        __syncthreads();
        sh[t] += u;
        __syncthreads();
    }
    if (t < nbkt) bbase[t] = sh[t] - v;
    if (t == 0) { bbase[nbkt] = E; offsets[N] = E; }
}

// C: scatter edges into bucket regions as packed (src<<9)|d_local.
__global__ __launch_bounds__(256) void bucket_scatter_kernel(
        const int* __restrict__ src, const int* __restrict__ dst,
        const int* __restrict__ bbase, const int* __restrict__ blkoff,
        unsigned int* __restrict__ bkt, int E, int nbkt, int ebpb) {
    __shared__ int lbase[256];
    __shared__ int lrank[256];
    int t = threadIdx.x;
    if (t < nbkt) lbase[t] = bbase[t] + blkoff[(size_t)t * NBLK + blockIdx.x];
    lrank[t] = 0;
    __syncthreads();
    int base = blockIdx.x * ebpb;
    int end = min(base + ebpb, E);
    for (int i = base + t; i < end; i += 256) {
        int d = dst[i];
        int b = d >> 9;
        int r = atomicAdd(&lrank[b], 1);
        bkt[lbase[b] + r] = ((unsigned int)src[i] << 9) | (unsigned int)(d & (BS - 1));
    }
}

// D: block b = bucket b. LDS hist + scan -> offsets + csr (LDS atomics only).
__global__ __launch_bounds__(256) void csr_build_kernel(
        const unsigned int* __restrict__ bkt, const int* __restrict__ bbase,
        int* __restrict__ offsets, int* __restrict__ csr, int N, int nbkt) {
    __shared__ int cnt[BS];
    __shared__ int rank[BS];
    __shared__ int sh[256];
    int b = blockIdx.x, t = threadIdx.x;
    cnt[t] = 0; cnt[t + 256] = 0;
    rank[t] = 0; rank[t + 256] = 0;
    __syncthreads();
    int base = bbase[b], end = bbase[b + 1];
    for (int i = base + t; i < end; i += 256)
        atomicAdd(&cnt[bkt[i] & (BS - 1)], 1);
    __syncthreads();
    int i0 = 2 * t, i1 = 2 * t + 1;
    int v0 = cnt[i0], v1 = cnt[i1];
    int pair = v0 + v1;
    sh[t] = pair;
    __syncthreads();
    for (int off = 1; off < 256; off <<= 1) {
        int u = (t >= off) ? sh[t - off] : 0;
        __syncthreads();
        sh[t] += u;
        __syncthreads();
    }
    int ex = sh[t] - pair;
    __syncthreads();
    cnt[i0] = ex;
    cnt[i1] = ex + v0;
    __syncthreads();
    int d0 = (b << 9) + i0;
    if (d0 <= N) offsets[d0] = base + cnt[i0];
    int d1 = (b << 9) + i1;
    if (d1 <= N) offsets[d1] = base + cnt[i1];
    for (int i = base + t; i < end; i += 256) {
        unsigned int v = bkt[i];
        int dl = v & (BS - 1);
        int r = atomicAdd(&rank[dl], 1);
        csr[base + cnt[dl] + r] = (int)(v >> 9);
    }
}

// Fused GIN layer, R11 gather: wave = 16-node tile, 4 lane-groups x 4 passes.
// Per (group,pass): preload 32 csr indices into 2 regs (coalesced), then
// unroll-8 shfl+row-load gather (no in-loop csr dependency). deg>32 tail rare.
__global__ __launch_bounds__(256) void layer_kernel(
        const ushort_t* __restrict__ hin, ushort_t* __restrict__ hout,
        const int* __restrict__ offsets, const int* __restrict__ csr,
        const ushort_t* __restrict__ wt_hi, const ushort_t* __restrict__ wt_lo,
        const float* __restrict__ gin_b, const float* __restrict__ eps_arr,
        int layer, int N) {
    __shared__ float rows[4 * 16 * 64];   // 16KB: 4 waves x 16 nodes x 64 f32
    int t = threadIdx.x;
    int wv = t >> 6, lane = t & 63;
    int tile = blockIdx.x * 4 + wv;
    if (tile * 16 >= N) return;           // waves independent
    float* myrows = rows + wv * 16 * 64;
    float eps1 = 1.0f + eps_arr[layer];

    int nq = lane >> 4;        // group 0..3 (node within pass)
    int sl = lane & 15;        // uint2 slot (dims 4sl..4sl+3)
    int gbase = lane & 48;     // group's first lane

    // preload: per (pass,group) node, 32 indices across the group's 16 lanes
    int e0[4], dg[4], idxA[4], idxB[4];
    #pragma unroll
    for (int p = 0; p < 4; ++p) {
        int node = tile * 16 + p * 4 + nq;
        int cn = min(node, N - 1);
        int a = offsets[cn], b = offsets[cn + 1];
        e0[p] = a;
        dg[p] = (node < N) ? (b - a) : 0;
        idxA[p] = (sl < dg[p]) ? csr[a + sl] : 0;
        idxB[p] = (16 + sl < dg[p]) ? csr[a + 16 + sl] : 0;
    }

    #pragma unroll
    for (int p = 0; p < 4; ++p) {
        float ax = 0.f, ay = 0.f, az = 0.f, aw = 0.f;
        int d1 = min(dg[p], 16);
        #pragma unroll 8
        for (int j = 0; j < d1; ++j) {
            int s = __shfl(idxA[p], gbase + j, 64);
            uint2 v = ((const uint2*)(hin + (size_t)s * 64))[sl];
            ax += h2f_lo(v.x); ay += h2f_hi(v.x);
            az += h2f_lo(v.y); aw += h2f_hi(v.y);
        }
        int d2 = min(dg[p], 32);
        #pragma unroll 8
        for (int j = 16; j < d2; ++j) {
            int s = __shfl(idxB[p], gbase + (j - 16), 64);
            uint2 v = ((const uint2*)(hin + (size_t)s * 64))[sl];
            ax += h2f_lo(v.x); ay += h2f_hi(v.x);
            az += h2f_lo(v.y); aw += h2f_hi(v.y);
        }
        for (int e = e0[p] + 32; e < e0[p] + dg[p]; ++e) {   // rare: deg > 32
            int s = csr[e];
            uint2 v = ((const uint2*)(hin + (size_t)s * 64))[sl];
            ax += h2f_lo(v.x); ay += h2f_hi(v.x);
            az += h2f_lo(v.y); aw += h2f_hi(v.y);
        }
        int node = tile * 16 + p * 4 + nq;
        if (node < N) {
            uint2 self = ((const uint2*)(hin + (size_t)node * 64))[sl];
            ax = fmaf(eps1, h2f_lo(self.x), ax);
            ay = fmaf(eps1, h2f_hi(self.x), ay);
            az = fmaf(eps1, h2f_lo(self.y), az);
            aw = fmaf(eps1, h2f_hi(self.y), aw);
        }
        float4 r4; r4.x = ax; r4.y = ay; r4.z = az; r4.w = aw;
        *(float4*)&myrows[(p * 4 + nq) * 64 + sl * 4] = r4;
    }
    // intra-wave LDS ordering: compiler emits lgkmcnt before reads; no barrier.

    int c = lane & 15;     // node within tile / n-index
    int q = lane >> 4;     // quad
    int node16 = tile * 16 + c;

    const ushort_t* Whi = wt_hi + layer * 4096;
    const ushort_t* Wlo = wt_lo + layer * 4096;
    const float*    bl  = gin_b + layer * 64;

    v8bf bhi[2], blo2[2];
    #pragma unroll
    for (int kt = 0; kt < 2; ++kt) {
        float4 f0 = *(float4*)&myrows[c * 64 + kt * 32 + q * 8];
        float4 f1 = *(float4*)&myrows[c * 64 + kt * 32 + q * 8 + 4];
        float xs[8] = {f0.x, f0.y, f0.z, f0.w, f1.x, f1.y, f1.z, f1.w};
        #pragma unroll
        for (int j = 0; j < 8; ++j) {
            __bf16 h = (__bf16)xs[j];
            bhi[kt][j] = h;
            blo2[kt][j] = (__bf16)(xs[j] - (float)h);
        }
    }

    #pragma unroll
    for (int mt = 0; mt < 4; ++mt) {
        v4f acc = {0.f, 0.f, 0.f, 0.f};
        #pragma unroll
        for (int kt = 0; kt < 2; ++kt) {
            int dim = mt * 16 + c;
            size_t off = (size_t)dim * 64 + kt * 32 + q * 8;
            v8bf ah = __builtin_bit_cast(v8bf, *(const uint4*)(Whi + off));
            v8bf al = __builtin_bit_cast(v8bf, *(const uint4*)(Wlo + off));
            acc = __builtin_amdgcn_mfma_f32_16x16x32_bf16(ah, bhi[kt],  acc, 0, 0, 0);
            acc = __builtin_amdgcn_mfma_f32_16x16x32_bf16(ah, blo2[kt], acc, 0, 0, 0);
            acc = __builtin_amdgcn_mfma_f32_16x16x32_bf16(al, bhi[kt],  acc, 0, 0, 0);
        }
        float4 bv = ((const float4*)(bl + mt * 16))[q];
        float o0 = fmaxf(acc[0] + bv.x, 0.f);
        float o1 = fmaxf(acc[1] + bv.y, 0.f);
        float o2 = fmaxf(acc[2] + bv.z, 0.f);
        float o3 = fmaxf(acc[3] + bv.w, 0.f);
        uint2 pk;
        pk.x = f2h(o0) | (f2h(o1) << 16);
        pk.y = f2h(o2) | (f2h(o3) << 16);
        if (node16 < N)
            *(uint2*)(hout + (size_t)node16 * 64 + mt * 16 + q * 4) = pk;
    }
}

// Phase 1: dense partials, no atomics. gpart[(graph*SPLIT+sp)*192 + t].
__global__ __launch_bounds__(192) void readout_part_kernel(
        const ushort_t* __restrict__ H, const int* __restrict__ gids,
        float* __restrict__ gpart, int N) {
    int graph = blockIdx.x / SPLIT;
    int sp    = blockIdx.x % SPLIT;
    int lo = 0, hi = N;
    while (lo < hi) { int mid = (lo + hi) >> 1; if (gids[mid] < graph) lo = mid + 1; else hi = mid; }
    int start = lo;
    int lo2 = start, hi2 = N;
    while (lo2 < hi2) { int mid = (lo2 + hi2) >> 1; if (gids[mid] < graph + 1) lo2 = mid + 1; else hi2 = mid; }
    int end = lo2;
    int t = threadIdx.x;            // 0..191
    int l = t >> 6, d = t & 63;
    float acc = 0.0f;
    int cnt = end - start;
    if (cnt > 0) {
        int per = (cnt + SPLIT - 1) / SPLIT;
        int cs = start + sp * per;
        int ce = min(cs + per, end);
        const ushort_t* Hl = H + (size_t)l * N * 64;
        for (int n = cs; n < ce; ++n)
            acc += (float)__builtin_bit_cast(_Float16, Hl[(size_t)n * 64 + d]);
    }
    gpart[(size_t)(graph * SPLIT + sp) * 192 + t] = acc;   // unconditional
}

// Phase 2 fused with MLP: sum 16 partials -> gr, then 2-layer MLP.
__global__ __launch_bounds__(192) void mlp_kernel(
        const float* __restrict__ gpart,
        const float* __restrict__ W1, const float* __restrict__ b1,
        const float* __restrict__ W2, const float* __restrict__ b2,
        float* __restrict__ out) {
    __shared__ float gr[192];
    __shared__ float hid[128];
    int graph = blockIdx.x;
    int t = threadIdx.x;
    float a = 0.f;
    #pragma unroll
    for (int sp = 0; sp < SPLIT; ++sp)
        a += gpart[(size_t)(graph * SPLIT + sp) * 192 + t];
    gr[t] = a;
    __syncthreads();
    if (t < 128) {
        float s = b1[t];
        for (int k = 0; k < 192; ++k) s = fmaf(gr[k], W1[k * 128 + t], s);
        hid[t] = fmaxf(s, 0.0f);
    }
    __syncthreads();
    if (t < 32) {
        float s = b2[t];
        for (int k = 0; k < 128; ++k) s = fmaf(hid[k], W2[k * 32 + t], s);
        out[graph * 32 + t] = s;
    }
}

extern "C" void kernel_launch(void* const* d_in, const int* in_sizes, int n_in,
                              void* d_out, int out_size, void* d_ws, size_t ws_size,
                              hipStream_t stream) {
    const float* x     = (const float*)d_in[0];
    const float* gin_W = (const float*)d_in[1];
    const float* gin_b = (const float*)d_in[2];
    const float* eps   = (const float*)d_in[3];
    const float* r_W1  = (const float*)d_in[4];
    const float* r_b1  = (const float*)d_in[5];
    const float* r_W2  = (const float*)d_in[6];
    const float* r_b2  = (const float*)d_in[7];
    const int*   src   = (const int*)d_in[8];
    const int*   dst   = (const int*)d_in[9];
    const int*   gids  = (const int*)d_in[10];

    int N = in_sizes[0] / 64;       // 100000
    int E = in_sizes[8];            // 1200000
    int B = out_size / 32;          // 256

    int nbkt = (N + BS - 1) / BS;   // 196 (<= 256)
    int ebpb = (E + NBLK - 1) / NBLK;

    // workspace layout (4B words), all regions fully written before read:
    //   gpart[B*SPLIT*192]
    //   cnt2d[NBLK*nbkt] | blkoff[nbkt*NBLK] | btot[nbkt] | bbase[nbkt+1]
    //   offsets[N+1] | bkt[E] | csr[E] | pad
    //   xh[N*64 f16] | H[3*N*64 f16] | whi[3*4096] | wlo[3*4096]
    int* ws       = (int*)d_ws;
    float* gpart  = (float*)ws;
    int* cnt2d    = ws + (size_t)B * SPLIT * 192;
    int* blkoff   = cnt2d + (size_t)NBLK * nbkt;
    int* btot     = blkoff + (size_t)nbkt * NBLK;
    int* bbase    = btot + nbkt;
    int* offsets  = bbase + (nbkt + 1);
    unsigned int* bkt = (unsigned int*)(offsets + (N + 1));
    int* csr      = (int*)(bkt + E);
    size_t w      = (size_t)(csr + E - ws);
    w = (w + 15) & ~(size_t)15;     // 64B align
    ushort_t* xh  = (ushort_t*)(ws + w);
    ushort_t* H   = xh + (size_t)N * 64;
    ushort_t* whi = H + 3 * (size_t)N * 64;
    ushort_t* wlo = whi + 3 * 4096;

    cast_kernel<<<(N * 64 / 4 + 255) / 256, 256, 0, stream>>>(x, xh, N * 64 / 4);
    prep_w_kernel<<<(3 * 4096 + 255) / 256, 256, 0, stream>>>(gin_W, whi, wlo, 3 * 4096);
    bucket_count_kernel<<<NBLK, 256, 0, stream>>>(dst, cnt2d, E, nbkt, ebpb);
    colscan_kernel<<<nbkt, 256, 0, stream>>>(cnt2d, blkoff, btot, nbkt);
    bucket_base_kernel<<<1, 256, 0, stream>>>(btot, bbase, offsets, nbkt, N, E);
    bucket_scatter_kernel<<<NBLK, 256, 0, stream>>>(src, dst, bbase, blkoff, bkt, E, nbkt, ebpb);
    csr_build_kernel<<<nbkt, 256, 0, stream>>>(bkt, bbase, offsets, csr, N, nbkt);

    int lbk = (N + 63) / 64;        // 4 tiles (waves) of 16 nodes per block
    ushort_t* H0 = H;
    ushort_t* H1 = H + (size_t)N * 64;
    ushort_t* H2 = H + 2 * (size_t)N * 64;

    layer_kernel<<<lbk, 256, 0, stream>>>(xh, H0, offsets, csr, whi, wlo, gin_b, eps, 0, N);
    layer_kernel<<<lbk, 256, 0, stream>>>(H0, H1, offsets, csr, whi, wlo, gin_b, eps, 1, N);
    layer_kernel<<<lbk, 256, 0, stream>>>(H1, H2, offsets, csr, whi, wlo, gin_b, eps, 2, N);

    readout_part_kernel<<<B * SPLIT, 192, 0, stream>>>(H, gids, gpart, N);
    mlp_kernel<<<B, 192, 0, stream>>>(gpart, r_W1, r_b1, r_W2, r_b2, (float*)d_out);
}